// Round 4
// baseline (91.465 us; speedup 1.0000x reference)
//
#include <hip/hip_runtime.h>
#include <hip/hip_bf16.h>
#include <stdint.h>

// dist2[b,f] = sum_d s2[f,d]*x2[b,d] - 2*sum_d s2*mu*x + c[f]
//  => GEMM M=4096 N=512 K=1024, bf16 A=[x2|x] built ON THE FLY from x,
//     bf16 W=[s2|-2*s2*mu] materialized once (1 MB).
#define BB 4096
#define FF 512
#define DD 512
#define KDIM 1024

typedef __bf16 bf16x8 __attribute__((ext_vector_type(8)));
typedef float f32x4 __attribute__((ext_vector_type(4)));
typedef unsigned short u16x8 __attribute__((ext_vector_type(8)));

__device__ __forceinline__ unsigned short f2bf(float f) {
  unsigned u = __builtin_bit_cast(unsigned, f);
  u += 0x7FFFu + ((u >> 16) & 1u);   // RNE
  return (unsigned short)(u >> 16);
}

__device__ __forceinline__ void async16(const void* g, void* l) {
  auto gp = reinterpret_cast<const __attribute__((address_space(1))) uint32_t*>(
      reinterpret_cast<uintptr_t>(g));
  auto lp = reinterpret_cast<__attribute__((address_space(3))) uint32_t*>(
      reinterpret_cast<uintptr_t>(l));
  __builtin_amdgcn_global_load_lds(gp, lp, 16, 0, 0);
}

// ---------------- prep: W + c only (A is built inside the GEMM now)
__global__ __launch_bounds__(256) void prep_kernel(
    const float* __restrict__ mu, const float* __restrict__ sg,
    unsigned short* __restrict__ W, float* __restrict__ c) {
  __shared__ float red[4];
  const int f = blockIdx.x;
  const int t = threadIdx.x;
  float part = 0.f;
#pragma unroll
  for (int dd = 0; dd < 2; ++dd) {
    const int d = t + dd * 256;
    const float m = mu[f * DD + d];
    const float s = sg[f * DD + d];
    const float s2 = s * s;
    W[f * KDIM + d] = f2bf(s2);
    W[f * KDIM + DD + d] = f2bf(-2.f * s2 * m);
    part += s2 * m * m;
  }
#pragma unroll
  for (int off = 32; off > 0; off >>= 1) part += __shfl_down(part, off, 64);
  const int lane = t & 63, wave = t >> 6;
  if (lane == 0) red[wave] = part;
  __syncthreads();
  if (t == 0) c[f] = red[0] + red[1] + red[2] + red[3];
}

// ---------------- GEMM: block 64(M)x128(N), 4 waves each 64x32, BK=64, dbuf.
// A-tile built on the fly: fp32 x loads -> bf16 (square for k<512) -> swizzled
// ds_write_b128. W-tile staged via global_load_lds (16B). LDS column-XOR
// swizzle: 16B chunk at logical c16 of row r lives at phys c16 ^ (r&7).
__global__ __launch_bounds__(256) void gemm_kernel(
    const float* __restrict__ x, const unsigned short* __restrict__ W,
    const float* __restrict__ c, float* __restrict__ out) {
  __shared__ __align__(16) unsigned short As[2][64 * 64];
  __shared__ __align__(16) unsigned short Bs[2][128 * 64];
  const int m0 = blockIdx.y * 64;
  const int n0 = blockIdx.x * 128;
  const int tid = threadIdx.x;
  const int lane = tid & 63;
  const int wave = tid >> 6;

  f32x4 acc[4][2];
#pragma unroll
  for (int i = 0; i < 4; ++i)
#pragma unroll
    for (int j = 0; j < 2; ++j) acc[i][j] = (f32x4){0.f, 0.f, 0.f, 0.f};

  // W staging (async16): lane -> (row srow, swizzled 16B chunk)
  const int srow = lane >> 3;
  const int sc16 = lane & 7;
  const int gcol = (sc16 ^ srow) * 8;
  const unsigned short* wg = W + (size_t)(n0 + wave * 32 + srow) * KDIM + gcol;
  const int brb = wave * 32;

  // A staging (registers): thread t covers row t>>2, 16 cols at (t&3)*16
  const int arow = tid >> 2;
  const int acg = (tid & 3) * 16;
  const float* xrow = x + (size_t)(m0 + arow) * DD;
  const int ac0 = acg >> 3;            // logical 16B chunk of q0
  const int asz = arow & 7;            // row swizzle key
  const int abase = arow * 64;

  const int quad = lane >> 4;
  const int r = lane & 15;
  const int wn = wave * 32;

  float4 xv0, xv1, xv2, xv3;
  // ---- prologue: tile 0 (square mode, xk0 = 0)
  xv0 = *(const float4*)(xrow + acg);
  xv1 = *(const float4*)(xrow + acg + 4);
  xv2 = *(const float4*)(xrow + acg + 8);
  xv3 = *(const float4*)(xrow + acg + 12);
#pragma unroll
  for (int tI = 0; tI < 4; ++tI)
    async16(wg + (size_t)tI * 8 * KDIM, &Bs[0][(brb + tI * 8) * 64]);
  {
    u16x8 q0, q1;
    q0[0] = f2bf(xv0.x * xv0.x); q0[1] = f2bf(xv0.y * xv0.y);
    q0[2] = f2bf(xv0.z * xv0.z); q0[3] = f2bf(xv0.w * xv0.w);
    q0[4] = f2bf(xv1.x * xv1.x); q0[5] = f2bf(xv1.y * xv1.y);
    q0[6] = f2bf(xv1.z * xv1.z); q0[7] = f2bf(xv1.w * xv1.w);
    q1[0] = f2bf(xv2.x * xv2.x); q1[1] = f2bf(xv2.y * xv2.y);
    q1[2] = f2bf(xv2.z * xv2.z); q1[3] = f2bf(xv2.w * xv2.w);
    q1[4] = f2bf(xv3.x * xv3.x); q1[5] = f2bf(xv3.y * xv3.y);
    q1[6] = f2bf(xv3.z * xv3.z); q1[7] = f2bf(xv3.w * xv3.w);
    *(u16x8*)&As[0][abase + ((ac0 ^ asz) << 3)] = q0;
    *(u16x8*)&As[0][abase + (((ac0 + 1) ^ asz) << 3)] = q1;
  }

  for (int kt = 0; kt < KDIM / 64; ++kt) {
    const int cur = kt & 1;
    const int nxt = cur ^ 1;
    __syncthreads();  // buf[cur] fully staged; buf[nxt] free to overwrite
    const bool pf = (kt + 1) < KDIM / 64;
    if (pf) {
      // x loads FIRST (older in vmcnt queue than W's async16 -> convert can
      // wait on them without draining W's in-flight loads)
      const int xk1 = ((kt + 1) < 8) ? (kt + 1) * 64 : (kt + 1) * 64 - 512;
      xv0 = *(const float4*)(xrow + xk1 + acg);
      xv1 = *(const float4*)(xrow + xk1 + acg + 4);
      xv2 = *(const float4*)(xrow + xk1 + acg + 8);
      xv3 = *(const float4*)(xrow + xk1 + acg + 12);
      const int k1 = (kt + 1) * 64;
#pragma unroll
      for (int tI = 0; tI < 4; ++tI)
        async16(wg + (size_t)tI * 8 * KDIM + k1, &Bs[nxt][(brb + tI * 8) * 64]);
    }
    // ---- MFMA phase on buf[cur]
#pragma unroll
    for (int kk = 0; kk < 2; ++kk) {
      const int pc = ((kk * 4 + quad) ^ (r & 7)) * 8;
      bf16x8 b0 = *(const bf16x8*)&Bs[cur][(wn + r) * 64 + pc];
      bf16x8 b1 = *(const bf16x8*)&Bs[cur][(wn + 16 + r) * 64 + pc];
#pragma unroll
      for (int mt = 0; mt < 4; ++mt) {
        bf16x8 a = *(const bf16x8*)&As[cur][(mt * 16 + r) * 64 + pc];
        acc[mt][0] = __builtin_amdgcn_mfma_f32_16x16x32_bf16(a, b0, acc[mt][0], 0, 0, 0);
        acc[mt][1] = __builtin_amdgcn_mfma_f32_16x16x32_bf16(a, b1, acc[mt][1], 0, 0, 0);
      }
    }
    // ---- convert + stage A tile kt+1
    if (pf) {
      const bool sq = (kt + 1) < 8;
      u16x8 q0, q1;
      if (sq) {
        q0[0] = f2bf(xv0.x * xv0.x); q0[1] = f2bf(xv0.y * xv0.y);
        q0[2] = f2bf(xv0.z * xv0.z); q0[3] = f2bf(xv0.w * xv0.w);
        q0[4] = f2bf(xv1.x * xv1.x); q0[5] = f2bf(xv1.y * xv1.y);
        q0[6] = f2bf(xv1.z * xv1.z); q0[7] = f2bf(xv1.w * xv1.w);
        q1[0] = f2bf(xv2.x * xv2.x); q1[1] = f2bf(xv2.y * xv2.y);
        q1[2] = f2bf(xv2.z * xv2.z); q1[3] = f2bf(xv2.w * xv2.w);
        q1[4] = f2bf(xv3.x * xv3.x); q1[5] = f2bf(xv3.y * xv3.y);
        q1[6] = f2bf(xv3.z * xv3.z); q1[7] = f2bf(xv3.w * xv3.w);
      } else {
        q0[0] = f2bf(xv0.x); q0[1] = f2bf(xv0.y);
        q0[2] = f2bf(xv0.z); q0[3] = f2bf(xv0.w);
        q0[4] = f2bf(xv1.x); q0[5] = f2bf(xv1.y);
        q0[6] = f2bf(xv1.z); q0[7] = f2bf(xv1.w);
        q1[0] = f2bf(xv2.x); q1[1] = f2bf(xv2.y);
        q1[2] = f2bf(xv2.z); q1[3] = f2bf(xv2.w);
        q1[4] = f2bf(xv3.x); q1[5] = f2bf(xv3.y);
        q1[6] = f2bf(xv3.z); q1[7] = f2bf(xv3.w);
      }
      *(u16x8*)&As[nxt][abase + ((ac0 ^ asz) << 3)] = q0;
      *(u16x8*)&As[nxt][abase + (((ac0 + 1) ^ asz) << 3)] = q1;
    }
  }

  // epilogue: D layout col=lane&15, row=quad*4+reg
  const int col = lane & 15;
#pragma unroll
  for (int nt = 0; nt < 2; ++nt) {
    const int f = n0 + wn + nt * 16 + col;
    const float cf = c[f];
#pragma unroll
    for (int mt = 0; mt < 4; ++mt) {
      const int mbase = m0 + mt * 16 + quad * 4;
#pragma unroll
      for (int rr = 0; rr < 4; ++rr) {
        const float d2 = acc[mt][nt][rr] + cf;
        const float loc = __expf(-sqrtf(fmaxf(d2, 0.f)));
        out[(size_t)(mbase + rr) * FF + f] = loc;
      }
    }
  }
}

// ---------------- softmax: 4 rows/block, one wave per row, in-place
__global__ __launch_bounds__(256) void softmax_kernel(
    float* __restrict__ out, const float* __restrict__ temp) {
  const int lane = threadIdx.x & 63;
  const int wave = threadIdx.x >> 6;
  const int row = blockIdx.x * 4 + wave;
  const float s = 1.f / (1.f + __expf(-temp[0]));
  float4* p = (float4*)(out + (size_t)row * FF + lane * 8);
  const float4 v0 = p[0];
  const float4 v1 = p[1];
  float l[8] = {v0.x * s, v0.y * s, v0.z * s, v0.w * s,
                v1.x * s, v1.y * s, v1.z * s, v1.w * s};
  float mx = l[0];
#pragma unroll
  for (int i = 1; i < 8; ++i) mx = fmaxf(mx, l[i]);
#pragma unroll
  for (int off = 32; off > 0; off >>= 1) mx = fmaxf(mx, __shfl_xor(mx, off, 64));
  float e[8], sum = 0.f;
#pragma unroll
  for (int i = 0; i < 8; ++i) { e[i] = __expf(l[i] - mx); sum += e[i]; }
#pragma unroll
  for (int off = 32; off > 0; off >>= 1) sum += __shfl_xor(sum, off, 64);
  const float inv = 1.f / sum;
  float4 w0 = {e[0] * inv, e[1] * inv, e[2] * inv, e[3] * inv};
  float4 w1 = {e[4] * inv, e[5] * inv, e[6] * inv, e[7] * inv};
  p[0] = w0; p[1] = w1;
}

// ---------------- fallback (no workspace): fp32 direct
__global__ __launch_bounds__(256) void naive_loc(
    const float* __restrict__ x, const float* __restrict__ mu,
    const float* __restrict__ sg, float* __restrict__ out) {
  __shared__ float xs[DD];
  const int b = blockIdx.x;
  for (int d = threadIdx.x; d < DD; d += 256) xs[d] = x[(size_t)b * DD + d];
  __syncthreads();
  for (int f = threadIdx.x; f < FF; f += 256) {
    float acc = 0.f;
    for (int d = 0; d < DD; ++d) {
      const float s = sg[(size_t)f * DD + d];
      const float df = (xs[d] - mu[(size_t)f * DD + d]) * s;
      acc = fmaf(df, df, acc);
    }
    out[(size_t)b * FF + f] = __expf(-sqrtf(acc));
  }
}

extern "C" void kernel_launch(void* const* d_in, const int* in_sizes, int n_in,
                              void* d_out, int out_size, void* d_ws, size_t ws_size,
                              hipStream_t stream) {
  const float* x = (const float*)d_in[0];
  const float* mu = (const float*)d_in[1];
  const float* sg = (const float*)d_in[2];
  const float* temp = (const float*)d_in[3];
  float* out = (float*)d_out;

  const size_t needW = (size_t)FF * KDIM * 2;          // 1 MB
  const size_t needC = (size_t)FF * 4;                 // 2 KB
  if (ws_size >= needW + needC) {
    unsigned short* W = (unsigned short*)d_ws;
    float* c = (float*)(W + (size_t)FF * KDIM);
    prep_kernel<<<FF, 256, 0, stream>>>(mu, sg, W, c);
    gemm_kernel<<<dim3(FF / 128, BB / 64), 256, 0, stream>>>(x, W, c, out);
  } else {
    naive_loc<<<BB, 256, 0, stream>>>(x, mu, sg, out);
  }
  softmax_kernel<<<BB / 4, 256, 0, stream>>>(out, temp);
}

// Round 5
// 84.987 us; speedup vs baseline: 1.0762x; 1.0762x over previous
//
#include <hip/hip_runtime.h>
#include <hip/hip_bf16.h>
#include <stdint.h>

// dist2[b,f] = sum_d s2[f,d]*x2[b,d] - 2*sum_d s2*mu*x + c[f]
//  => GEMM M=4096 N=512 K=1024, bf16 operands A=[x2|x], W=[s2|-2*s2*mu].
// R4 post-mortem: fusing the A-build into the GEMM regressed +5.2us (4x
// redundant convert, VALU in MFMA critical path). This is the R2 config —
// best measured (85.3us): separate prep, dbuf 64x128 GEMM, wave softmax.
#define BB 4096
#define FF 512
#define DD 512
#define KDIM 1024

typedef __bf16 bf16x8 __attribute__((ext_vector_type(8)));
typedef float f32x4 __attribute__((ext_vector_type(4)));
typedef unsigned short u16x8 __attribute__((ext_vector_type(8)));

__device__ __forceinline__ unsigned short f2bf(float f) {
  unsigned u = __builtin_bit_cast(unsigned, f);
  u += 0x7FFFu + ((u >> 16) & 1u);   // RNE
  return (unsigned short)(u >> 16);
}

__device__ __forceinline__ void async16(const void* g, void* l) {
  auto gp = reinterpret_cast<const __attribute__((address_space(1))) uint32_t*>(
      reinterpret_cast<uintptr_t>(g));
  auto lp = reinterpret_cast<__attribute__((address_space(3))) uint32_t*>(
      reinterpret_cast<uintptr_t>(l));
  __builtin_amdgcn_global_load_lds(gp, lp, 16, 0, 0);
}

// ---------------- prep: blocks [0,512) build W + c; blocks [512,1536) build A
__global__ __launch_bounds__(256) void prep_kernel(
    const float* __restrict__ x, const float* __restrict__ mu,
    const float* __restrict__ sg, unsigned short* __restrict__ A,
    unsigned short* __restrict__ W, float* __restrict__ c) {
  __shared__ float red[4];
  const int bid = blockIdx.x;
  const int t = threadIdx.x;
  if (bid < FF) {
    const int f = bid;
    float part = 0.f;
#pragma unroll
    for (int dd = 0; dd < 2; ++dd) {
      const int d = t + dd * 256;
      const float m = mu[f * DD + d];
      const float s = sg[f * DD + d];
      const float s2 = s * s;
      W[f * KDIM + d] = f2bf(s2);
      W[f * KDIM + DD + d] = f2bf(-2.f * s2 * m);
      part += s2 * m * m;
    }
#pragma unroll
    for (int off = 32; off > 0; off >>= 1) part += __shfl_down(part, off, 64);
    const int lane = t & 63, wave = t >> 6;
    if (lane == 0) red[wave] = part;
    __syncthreads();
    if (t == 0) c[f] = red[0] + red[1] + red[2] + red[3];
  } else {
    const int gid = (bid - FF) * 256 + t;     // 1024 blocks cover B*D/8
    const int i8 = gid * 8;
    const float4 v0 = *(const float4*)(x + i8);
    const float4 v1 = *(const float4*)(x + i8 + 4);
    const int b = i8 >> 9;
    const int d = i8 & 511;
    u16x8 q2, q1;
    q2[0] = f2bf(v0.x * v0.x); q2[1] = f2bf(v0.y * v0.y);
    q2[2] = f2bf(v0.z * v0.z); q2[3] = f2bf(v0.w * v0.w);
    q2[4] = f2bf(v1.x * v1.x); q2[5] = f2bf(v1.y * v1.y);
    q2[6] = f2bf(v1.z * v1.z); q2[7] = f2bf(v1.w * v1.w);
    q1[0] = f2bf(v0.x); q1[1] = f2bf(v0.y); q1[2] = f2bf(v0.z); q1[3] = f2bf(v0.w);
    q1[4] = f2bf(v1.x); q1[5] = f2bf(v1.y); q1[6] = f2bf(v1.z); q1[7] = f2bf(v1.w);
    *(u16x8*)(A + (size_t)b * KDIM + d) = q2;
    *(u16x8*)(A + (size_t)b * KDIM + DD + d) = q1;
  }
}

// ---------------- GEMM: block 64(M)x128(N), 4 waves each 64x32, BK=64, dbuf.
// Grid = 4 x 64 = 256 blocks = 1/CU. Per wave per K-iter: 16 MFMA vs
// 12 ds_read_b128. LDS column-XOR swizzle: 16B chunk at logical c16 of row r
// lives at phys c16 ^ (r&7); staging fetches the matching global column since
// global_load_lds forces LDS dest = base + lane*16.
__global__ __launch_bounds__(256) void gemm_kernel(
    const unsigned short* __restrict__ A, const unsigned short* __restrict__ W,
    const float* __restrict__ c, float* __restrict__ out) {
  __shared__ __align__(16) unsigned short As[2][64 * 64];
  __shared__ __align__(16) unsigned short Bs[2][128 * 64];
  const int m0 = blockIdx.y * 64;
  const int n0 = blockIdx.x * 128;
  const int tid = threadIdx.x;
  const int lane = tid & 63;
  const int wave = tid >> 6;

  f32x4 acc[4][2];
#pragma unroll
  for (int i = 0; i < 4; ++i)
#pragma unroll
    for (int j = 0; j < 2; ++j) acc[i][j] = (f32x4){0.f, 0.f, 0.f, 0.f};

  const int srow = lane >> 3;          // 0..7 within 8-row staging group
  const int sc16 = lane & 7;           // phys 16B chunk this lane fills
  const int gcol = (sc16 ^ srow) * 8;  // logical column (elements) to fetch
  const int quad = lane >> 4;
  const int r = lane & 15;
  const int wn = wave * 32;            // wave's N-slice within the 128 cols

  const unsigned short* ag = A + (size_t)(m0 + wave * 16 + srow) * KDIM + gcol;
  const unsigned short* wg = W + (size_t)(n0 + wave * 32 + srow) * KDIM + gcol;
  const int arb = wave * 16;
  const int brb = wave * 32;

  // prologue: stage k-slice 0 into buf 0
#pragma unroll
  for (int tI = 0; tI < 2; ++tI)
    async16(ag + (size_t)tI * 8 * KDIM, &As[0][(arb + tI * 8) * 64]);
#pragma unroll
  for (int tI = 0; tI < 4; ++tI)
    async16(wg + (size_t)tI * 8 * KDIM, &Bs[0][(brb + tI * 8) * 64]);

  for (int kt = 0; kt < KDIM / 64; ++kt) {
    const int cur = kt & 1;
    __syncthreads();  // buf[cur] staged; everyone done reading buf[cur^1]
    if (kt + 1 < KDIM / 64) {
      const int k1 = (kt + 1) * 64;
#pragma unroll
      for (int tI = 0; tI < 2; ++tI)
        async16(ag + (size_t)tI * 8 * KDIM + k1, &As[cur ^ 1][(arb + tI * 8) * 64]);
#pragma unroll
      for (int tI = 0; tI < 4; ++tI)
        async16(wg + (size_t)tI * 8 * KDIM + k1, &Bs[cur ^ 1][(brb + tI * 8) * 64]);
    }
#pragma unroll
    for (int kk = 0; kk < 2; ++kk) {
      const int pc = ((kk * 4 + quad) ^ (r & 7)) * 8;  // swizzled phys column
      bf16x8 b0 = *(const bf16x8*)&Bs[cur][(wn + r) * 64 + pc];
      bf16x8 b1 = *(const bf16x8*)&Bs[cur][(wn + 16 + r) * 64 + pc];
#pragma unroll
      for (int mt = 0; mt < 4; ++mt) {
        bf16x8 a = *(const bf16x8*)&As[cur][(mt * 16 + r) * 64 + pc];
        acc[mt][0] = __builtin_amdgcn_mfma_f32_16x16x32_bf16(a, b0, acc[mt][0], 0, 0, 0);
        acc[mt][1] = __builtin_amdgcn_mfma_f32_16x16x32_bf16(a, b1, acc[mt][1], 0, 0, 0);
      }
    }
  }

  // epilogue: D layout col=lane&15, row=quad*4+reg
  const int col = lane & 15;
#pragma unroll
  for (int nt = 0; nt < 2; ++nt) {
    const int f = n0 + wn + nt * 16 + col;
    const float cf = c[f];
#pragma unroll
    for (int mt = 0; mt < 4; ++mt) {
      const int mbase = m0 + mt * 16 + quad * 4;
#pragma unroll
      for (int rr = 0; rr < 4; ++rr) {
        const float d2 = acc[mt][nt][rr] + cf;
        const float loc = __expf(-sqrtf(fmaxf(d2, 0.f)));
        out[(size_t)(mbase + rr) * FF + f] = loc;
      }
    }
  }
}

// ---------------- softmax: 4 rows/block, one wave per row, in-place
__global__ __launch_bounds__(256) void softmax_kernel(
    float* __restrict__ out, const float* __restrict__ temp) {
  const int lane = threadIdx.x & 63;
  const int wave = threadIdx.x >> 6;
  const int row = blockIdx.x * 4 + wave;
  const float s = 1.f / (1.f + __expf(-temp[0]));
  float4* p = (float4*)(out + (size_t)row * FF + lane * 8);
  const float4 v0 = p[0];
  const float4 v1 = p[1];
  float l[8] = {v0.x * s, v0.y * s, v0.z * s, v0.w * s,
                v1.x * s, v1.y * s, v1.z * s, v1.w * s};
  float mx = l[0];
#pragma unroll
  for (int i = 1; i < 8; ++i) mx = fmaxf(mx, l[i]);
#pragma unroll
  for (int off = 32; off > 0; off >>= 1) mx = fmaxf(mx, __shfl_xor(mx, off, 64));
  float e[8], sum = 0.f;
#pragma unroll
  for (int i = 0; i < 8; ++i) { e[i] = __expf(l[i] - mx); sum += e[i]; }
#pragma unroll
  for (int off = 32; off > 0; off >>= 1) sum += __shfl_xor(sum, off, 64);
  const float inv = 1.f / sum;
  float4 w0 = {e[0] * inv, e[1] * inv, e[2] * inv, e[3] * inv};
  float4 w1 = {e[4] * inv, e[5] * inv, e[6] * inv, e[7] * inv};
  p[0] = w0; p[1] = w1;
}

// ---------------- fallback (no workspace): fp32 direct
__global__ __launch_bounds__(256) void naive_loc(
    const float* __restrict__ x, const float* __restrict__ mu,
    const float* __restrict__ sg, float* __restrict__ out) {
  __shared__ float xs[DD];
  const int b = blockIdx.x;
  for (int d = threadIdx.x; d < DD; d += 256) xs[d] = x[(size_t)b * DD + d];
  __syncthreads();
  for (int f = threadIdx.x; f < FF; f += 256) {
    float acc = 0.f;
    for (int d = 0; d < DD; ++d) {
      const float s = sg[(size_t)f * DD + d];
      const float df = (xs[d] - mu[(size_t)f * DD + d]) * s;
      acc = fmaf(df, df, acc);
    }
    out[(size_t)b * FF + f] = __expf(-sqrtf(acc));
  }
}

extern "C" void kernel_launch(void* const* d_in, const int* in_sizes, int n_in,
                              void* d_out, int out_size, void* d_ws, size_t ws_size,
                              hipStream_t stream) {
  const float* x = (const float*)d_in[0];
  const float* mu = (const float*)d_in[1];
  const float* sg = (const float*)d_in[2];
  const float* temp = (const float*)d_in[3];
  float* out = (float*)d_out;

  const size_t needA = (size_t)BB * KDIM * 2;          // 8 MB
  const size_t needW = (size_t)FF * KDIM * 2;          // 1 MB
  const size_t needC = (size_t)FF * 4;                 // 2 KB
  if (ws_size >= needA + needW + needC) {
    unsigned short* A = (unsigned short*)d_ws;
    unsigned short* W = A + (size_t)BB * KDIM;
    float* c = (float*)(W + (size_t)FF * KDIM);
    prep_kernel<<<FF + (BB * DD / 8) / 256, 256, 0, stream>>>(x, mu, sg, A, W, c);
    gemm_kernel<<<dim3(FF / 128, BB / 64), 256, 0, stream>>>(A, W, c, out);
  } else {
    naive_loc<<<BB, 256, 0, stream>>>(x, mu, sg, out);
  }
  softmax_kernel<<<BB / 4, 256, 0, stream>>>(out, temp);
}